// Round 6
// baseline (447.675 us; speedup 1.0000x reference)
//
#include <hip/hip_runtime.h>

// PILayer: out = tanh((prop[idx_i] + basis + prop[idx_j]) @ W1 + b1) @ W2 + b2
// E=320000, D_IN=128, D_HID=256, D_OUT=128. fp32 in/out, fp16 MFMA internally.
//
// Round-6 design: LEAN kernel, occupancy-first. Measured law (rounds 2-5):
// waves/SIMD = floor(256/VGPR_Count) with MFMA kernels on this stack, and
// HBM BW scales ~linearly with resident waves (~92 GB/s per occupancy-pt).
// So: TM=32 tile, 256 threads, NO register prefetch pipeline (it cost 128+
// VGPRs), LDS 25.6 KB. Target VGPR <= 84 -> 3 blocks/CU = 12 waves/CU
// (vs 3.6-7.2 waves in rounds 2/4/5). Gather latency hidden by block TLP.
// 10000 independent blocks, one tile each.

#define N_EDGES 320000
#define DI 128
#define DH 256
#define DO 128
#define TM 32                    // edges per tile

typedef _Float16 half8v __attribute__((ext_vector_type(8)));
typedef _Float16 half4v __attribute__((ext_vector_type(4)));
typedef float floatx16 __attribute__((ext_vector_type(16)));

__device__ __forceinline__ float fast_tanh(float x) {
    float ax = __builtin_fabsf(x);
    float e = __expf(2.0f * ax);                       // v_mul + v_exp_f32
    float t = 1.0f - 2.0f * __builtin_amdgcn_rcpf(e + 1.0f);
    return __builtin_copysignf(t, x);
}

// Barrier draining LDS ops only (vmem naturally drained by data deps here).
#define BAR() do { asm volatile("s_waitcnt lgkmcnt(0)" ::: "memory"); \
                   __builtin_amdgcn_s_barrier();                      \
                   asm volatile("" ::: "memory"); } while (0)

// ---------------------------------------------------------------------------
// Prologue: transpose+convert W1[128][256] -> W1T fp16 [256][128],
//                             W2[256][128] -> W2T fp16 [128][256]
// ---------------------------------------------------------------------------
__global__ __launch_bounds__(256) void wconvert(
    const float* __restrict__ W1, const float* __restrict__ W2,
    _Float16* __restrict__ W1T, _Float16* __restrict__ W2T)
{
    __shared__ float sT[32][33];
    int b = blockIdx.x;
    const float* src; _Float16* dst; int R, C, r0, c0;
    if (b < 32) { src = W1; dst = W1T; R = DI;  C = DH; r0 = (b & 3) * 32;  c0 = (b >> 2) * 32; }
    else { b -= 32; src = W2; dst = W2T; R = DH; C = DO; r0 = (b & 7) * 32; c0 = (b >> 3) * 32; }

    const int tid = threadIdx.x;
    const int cc = tid & 31, rr = tid >> 5;
    #pragma unroll
    for (int p = 0; p < 4; ++p) {
        int r = rr + p * 8;
        sT[r][cc] = src[(size_t)(r0 + r) * C + c0 + cc];
    }
    __syncthreads();
    #pragma unroll
    for (int p = 0; p < 4; ++p) {
        int c = rr + p * 8;                 // dst row = src col
        dst[(size_t)(c0 + c) * R + r0 + cc] = (_Float16)sT[cc][c];
    }
}

// ---------------------------------------------------------------------------
// Main kernel: one block = one 32-edge tile, 4 waves, minimal registers.
//   stage inter(fp16) -> GEMM1 (B from global W1T) -> tanh -> sH
//   -> GEMM2 (B from global W2T) -> +b2 -> NT store
// mfma_f32_32x32x16_f16: A lane l: m=l&31, k=(l>>5)*8+j (contig 8)
//                        B lane l: n=l&31, k=(l>>5)*8+j (contig 8 in W^T)
//                        C/D lane l reg r: col=l&31, row=(r&3)+8*(r>>2)+4*(l>>5)
// ---------------------------------------------------------------------------
__global__ __launch_bounds__(256, 3) void pilayer_main(
    const int* __restrict__ idx_i, const int* __restrict__ idx_j,
    const float* __restrict__ prop, const float* __restrict__ basis,
    const _Float16* __restrict__ W1T, const float* __restrict__ b1,
    const _Float16* __restrict__ W2T, const float* __restrict__ b2,
    float* __restrict__ out)
{
    // stride pads: +8 fp16 keeps rows 16B-aligned and the 68-dword (mod32=4)
    // bank pattern -> conflict-free b128 reads (0 conflicts all prior rounds)
    __shared__ _Float16 sA[TM][DI + 8];    // 32 x 136 x 2B =  8704 B
    __shared__ _Float16 sH[TM][DH + 8];    // 32 x 264 x 2B = 16896 B (tot 25.6 KB)

    const int tid = threadIdx.x;
    const int e0  = blockIdx.x * TM;

    // ---- stage inter = prop[i] + basis + prop[j] as fp16 into sA ----
    // 1024 segments (32 rows x 32 col-quads), 4 per thread.
    {
        #pragma unroll
        for (int p = 0; p < 4; ++p) {
            const int s   = tid + p * 256;
            const int r   = s >> 5;          // 0..31
            const int c4  = (s & 31) * 4;    // 0..124
            const int e   = e0 + r;
            const int ii = idx_i[e], jj = idx_j[e];   // 32-lane broadcast
            const float4 a  = *(const float4*)(prop  + (size_t)ii * DI + c4);
            const float4 bv = *(const float4*)(prop  + (size_t)jj * DI + c4);
            const float4 c  = *(const float4*)(basis + (size_t)e  * DI + c4);
            half4v hv;
            hv[0] = (_Float16)(a.x + bv.x + c.x);
            hv[1] = (_Float16)(a.y + bv.y + c.y);
            hv[2] = (_Float16)(a.z + bv.z + c.z);
            hv[3] = (_Float16)(a.w + bv.w + c.w);
            *(half4v*)(&sA[r][c4]) = hv;
        }
    }
    BAR();

    const int w  = tid >> 6;       // wave 0..3
    const int l  = tid & 63;
    const int lm = l & 31;         // m / n within 32x32 tile
    const int lk = (l >> 5) * 8;   // k sub-offset
    const int rowq = 4 * (l >> 5); // row quad base for C/D layout

    // ---- GEMM1: h[32 x 256], wave w owns cols [w*64, w*64+64) ----
    floatx16 hacc[2] = {};         // 32 regs
    {
        const _Float16* w1p = W1T + (size_t)(w * 64 + lm) * DI + lk;
        __builtin_amdgcn_s_setprio(1);
        #pragma unroll 4
        for (int kt = 0; kt < 8; ++kt) {
            const int ko = kt * 16;
            half8v a0  = *(const half8v*)(&sA[lm][ko + lk]);
            half8v b0  = *(const half8v*)(w1p + ko);
            half8v b1f = *(const half8v*)(w1p + 32 * DI + ko);
            hacc[0] = __builtin_amdgcn_mfma_f32_32x32x16_f16(a0, b0,  hacc[0], 0, 0, 0);
            hacc[1] = __builtin_amdgcn_mfma_f32_32x32x16_f16(a0, b1f, hacc[1], 0, 0, 0);
        }
        __builtin_amdgcn_s_setprio(0);
    }

    // ---- bias + tanh, write h to sH (C-layout -> memory layout) ----
    {
        const float bias0 = b1[w * 64 + lm];
        const float bias1 = b1[w * 64 + 32 + lm];
        #pragma unroll
        for (int r = 0; r < 16; ++r) {
            const int row = (r & 3) + 8 * (r >> 2) + rowq;   // 0..31
            sH[row][w * 64 + lm]      = (_Float16)fast_tanh(hacc[0][r] + bias0);
            sH[row][w * 64 + 32 + lm] = (_Float16)fast_tanh(hacc[1][r] + bias1);
        }
    }
    BAR();

    // ---- GEMM2: out[32 x 128], wave w owns cols [w*32, w*32+32) ----
    floatx16 oacc = {};            // 16 regs
    {
        const _Float16* w2p = W2T + (size_t)(w * 32 + lm) * DH + lk;
        __builtin_amdgcn_s_setprio(1);
        #pragma unroll 4
        for (int kt = 0; kt < 16; ++kt) {
            const int ko = kt * 16;
            half8v a0 = *(const half8v*)(&sH[lm][ko + lk]);
            half8v bb = *(const half8v*)(w2p + ko);
            oacc = __builtin_amdgcn_mfma_f32_32x32x16_f16(a0, bb, oacc, 0, 0, 0);
        }
        __builtin_amdgcn_s_setprio(0);
    }

    // ---- epilogue: + b2, NT store fp32 (write-once stream) ----
    {
        const int col = w * 32 + lm;
        const float bias = b2[col];
        #pragma unroll
        for (int r = 0; r < 16; ++r) {
            const int row = e0 + (r & 3) + 8 * (r >> 2) + rowq;
            __builtin_nontemporal_store(oacc[r] + bias,
                                        out + (size_t)row * DO + col);
        }
    }
}

extern "C" void kernel_launch(void* const* d_in, const int* in_sizes, int n_in,
                              void* d_out, int out_size, void* d_ws, size_t ws_size,
                              hipStream_t stream) {
    const int*   idx_i = (const int*)d_in[0];
    const int*   idx_j = (const int*)d_in[1];
    const float* prop  = (const float*)d_in[2];
    const float* basis = (const float*)d_in[3];
    const float* W1    = (const float*)d_in[4];
    const float* b1    = (const float*)d_in[5];
    const float* W2    = (const float*)d_in[6];
    const float* b2    = (const float*)d_in[7];
    float* out = (float*)d_out;

    _Float16* W1T = (_Float16*)d_ws;            // [256][128] = 64 KB
    _Float16* W2T = W1T + (size_t)DI * DH;      // [128][256] = 64 KB

    wconvert<<<64, 256, 0, stream>>>(W1, W2, W1T, W2T);
    pilayer_main<<<N_EDGES / TM, 256, 0, stream>>>(idx_i, idx_j, prop, basis,
                                                   W1T, b1, W2T, b2, out);
}

// Round 7
// 403.815 us; speedup vs baseline: 1.1086x; 1.1086x over previous
//
#include <hip/hip_runtime.h>

// PILayer: out = tanh((prop[idx_i] + basis + prop[idx_j]) @ W1 + b1) @ W2 + b2
// E=320000, D_IN=128, D_HID=256, D_OUT=128. fp32 in/out, fp16 MFMA internally.
//
// Round-7 restructure: GEMM1 is linear, so
//   inter@W1 = basis@W1 + P1[idx_i] + P1[idx_j],  P1 = prop@W1 (precomputed).
// This removes the idx->gather chain from staging entirely (basis streams,
// no dependency), kills the 96-VGPR prefetch pipeline, and moves the gather
// to cheap post-GEMM1 P1 reads (L2/L3-resident, 10.2 MB) overlapped with
// tanh. P1 computed with hi/lo double-fp16 MFMA so it carries only
// W-rounding error (accuracy parity with the previous kernel).
// LDS 51.7 KB -> up to 3 blocks/CU; lean VGPR; 5000 independent blocks.

#define N_EDGES 320000
#define N_NODES 10000
#define DI 128
#define DH 256
#define DO 128
#define TM 64                    // edges per tile
#define NBLK (N_EDGES / TM)      // 5000

typedef _Float16 half8v __attribute__((ext_vector_type(8)));
typedef _Float16 half4v __attribute__((ext_vector_type(4)));
typedef float floatx16 __attribute__((ext_vector_type(16)));

__device__ __forceinline__ float fast_tanh(float x) {
    // tanh(x) = 1 - 2/(exp(2x)+1); exp->inf and exp->0 both give correct +/-1.
    float e = __expf(2.0f * x);
    return 1.0f - 2.0f * __builtin_amdgcn_rcpf(e + 1.0f);
}

// ---------------------------------------------------------------------------
// Prologue 1: transpose+convert W1[128][256] -> W1T fp16 [256][128],
//                               W2[256][128] -> W2T fp16 [128][256]
// ---------------------------------------------------------------------------
__global__ __launch_bounds__(256) void wconvert(
    const float* __restrict__ W1, const float* __restrict__ W2,
    _Float16* __restrict__ W1T, _Float16* __restrict__ W2T)
{
    __shared__ float sT[32][33];
    int b = blockIdx.x;
    const float* src; _Float16* dst; int R, C, r0, c0;
    if (b < 32) { src = W1; dst = W1T; R = DI;  C = DH; r0 = (b & 3) * 32;  c0 = (b >> 2) * 32; }
    else { b -= 32; src = W2; dst = W2T; R = DH; C = DO; r0 = (b & 7) * 32; c0 = (b >> 3) * 32; }

    const int tid = threadIdx.x;
    const int cc = tid & 31, rr = tid >> 5;
    #pragma unroll
    for (int p = 0; p < 4; ++p) {
        int r = rr + p * 8;
        sT[r][cc] = src[(size_t)(r0 + r) * C + c0 + cc];
    }
    __syncthreads();
    #pragma unroll
    for (int p = 0; p < 4; ++p) {
        int c = rr + p * 8;                 // dst row = src col
        dst[(size_t)(c0 + c) * R + r0 + cc] = (_Float16)sT[cc][c];
    }
}

// ---------------------------------------------------------------------------
// Prologue 2: P1 = prop @ W1, fp32 [10000][256], via hi/lo double-fp16 MFMA
// (prop = hi + lo exactly; P1 error ~ W1 fp16 rounding only).
// 157 blocks x 64 rows; tail rows clamped on load, guarded on store.
// mfma_f32_32x32x16_f16 layouts as in main kernel.
// ---------------------------------------------------------------------------
__global__ __launch_bounds__(256) void p1comp(
    const float* __restrict__ prop, const _Float16* __restrict__ W1T,
    float* __restrict__ P1)
{
    __shared__ _Float16 sHi[TM][DI + 8];
    __shared__ _Float16 sLo[TM][DI + 8];

    const int tid = threadIdx.x;
    const int e0  = blockIdx.x * TM;
    const int c4  = (tid & 31) * 4;
    const int r0  = tid >> 5;

    #pragma unroll
    for (int p = 0; p < 8; ++p) {
        const int r = r0 + p * 8;
        int n = e0 + r; if (n > N_NODES - 1) n = N_NODES - 1;
        const float4 a = *(const float4*)(prop + (size_t)n * DI + c4);
        half4v hi, lo;
        hi[0] = (_Float16)a.x; lo[0] = (_Float16)(a.x - (float)hi[0]);
        hi[1] = (_Float16)a.y; lo[1] = (_Float16)(a.y - (float)hi[1]);
        hi[2] = (_Float16)a.z; lo[2] = (_Float16)(a.z - (float)hi[2]);
        hi[3] = (_Float16)a.w; lo[3] = (_Float16)(a.w - (float)hi[3]);
        *(half4v*)(&sHi[r][c4]) = hi;
        *(half4v*)(&sLo[r][c4]) = lo;
    }
    __syncthreads();

    const int w  = tid >> 6, l = tid & 63;
    const int lm = l & 31, lk = (l >> 5) * 8, rowq = 4 * (l >> 5);

    floatx16 acc[2][2] = {};
    const _Float16* w1p = W1T + (size_t)(w * 64 + lm) * DI + lk;
    #pragma unroll 2
    for (int kt = 0; kt < 8; ++kt) {
        const int ko = kt * 16;
        half8v b0  = *(const half8v*)(w1p + ko);
        half8v b1f = *(const half8v*)(w1p + 32 * DI + ko);
        half8v h0  = *(const half8v*)(&sHi[lm][ko + lk]);
        half8v h1  = *(const half8v*)(&sHi[32 + lm][ko + lk]);
        half8v l0  = *(const half8v*)(&sLo[lm][ko + lk]);
        half8v l1  = *(const half8v*)(&sLo[32 + lm][ko + lk]);
        acc[0][0] = __builtin_amdgcn_mfma_f32_32x32x16_f16(h0, b0,  acc[0][0], 0, 0, 0);
        acc[0][0] = __builtin_amdgcn_mfma_f32_32x32x16_f16(l0, b0,  acc[0][0], 0, 0, 0);
        acc[1][0] = __builtin_amdgcn_mfma_f32_32x32x16_f16(h1, b0,  acc[1][0], 0, 0, 0);
        acc[1][0] = __builtin_amdgcn_mfma_f32_32x32x16_f16(l1, b0,  acc[1][0], 0, 0, 0);
        acc[0][1] = __builtin_amdgcn_mfma_f32_32x32x16_f16(h0, b1f, acc[0][1], 0, 0, 0);
        acc[0][1] = __builtin_amdgcn_mfma_f32_32x32x16_f16(l0, b1f, acc[0][1], 0, 0, 0);
        acc[1][1] = __builtin_amdgcn_mfma_f32_32x32x16_f16(h1, b1f, acc[1][1], 0, 0, 0);
        acc[1][1] = __builtin_amdgcn_mfma_f32_32x32x16_f16(l1, b1f, acc[1][1], 0, 0, 0);
    }

    #pragma unroll
    for (int mt = 0; mt < 2; ++mt) {
        #pragma unroll
        for (int r = 0; r < 16; ++r) {
            const int row = e0 + mt * 32 + (r & 3) + 8 * (r >> 2) + rowq;
            if (row < N_NODES) {
                P1[(size_t)row * DH + w * 64 + lm]      = acc[mt][0][r];
                P1[(size_t)row * DH + w * 64 + 32 + lm] = acc[mt][1][r];
            }
        }
    }
}

// ---------------------------------------------------------------------------
// Main kernel: one block = one 64-edge tile.
//   stream basis -> sA(fp16) -> GEMM1 (B=W1T global)
//   -> epilogue: + b1 + P1[idx_i] + P1[idx_j], tanh -> sH
//   -> GEMM2 (B=W2T global) -> +b2 -> NT store
// mfma_f32_32x32x16_f16: A lane l: m=l&31, k=(l>>5)*8+j (contig 8)
//                        B lane l: n=l&31, k=(l>>5)*8+j (contig 8 in W^T)
//                        C/D lane l reg r: col=l&31, row=(r&3)+8*(r>>2)+4*(l>>5)
// ---------------------------------------------------------------------------
__global__ __launch_bounds__(256) void pilayer_main(
    const int* __restrict__ idx_i, const int* __restrict__ idx_j,
    const float* __restrict__ basis, const float* __restrict__ P1,
    const _Float16* __restrict__ W1T, const float* __restrict__ b1,
    const _Float16* __restrict__ W2T, const float* __restrict__ b2,
    float* __restrict__ out)
{
    __shared__ _Float16 sA[TM][DI + 8];    // 17408 B
    __shared__ _Float16 sH[TM][DH + 8];    // 33792 B
    __shared__ int2 sIdx[TM];              // 512 B  (total 51712 B)

    const int tid = threadIdx.x;
    const int e0  = blockIdx.x * TM;
    const int c4  = (tid & 31) * 4;
    const int r0  = tid >> 5;

    // ---- stage basis (pure stream, no dependency) ----
    #pragma unroll
    for (int p = 0; p < 8; ++p) {
        const int r = r0 + p * 8;
        const float4 c = *(const float4*)(basis + (size_t)(e0 + r) * DI + c4);
        half4v hv;
        hv[0] = (_Float16)c.x; hv[1] = (_Float16)c.y;
        hv[2] = (_Float16)c.z; hv[3] = (_Float16)c.w;
        *(half4v*)(&sA[r][c4]) = hv;
    }
    if (tid < TM) sIdx[tid] = make_int2(idx_i[e0 + tid], idx_j[e0 + tid]);
    __syncthreads();

    const int w  = tid >> 6, l = tid & 63;
    const int lm = l & 31, lk = (l >> 5) * 8, rowq = 4 * (l >> 5);

    // ---- GEMM1: g = basis @ W1, wave w owns cols [w*64, w*64+64) ----
    floatx16 hacc[2][2] = {};
    {
        const _Float16* w1p = W1T + (size_t)(w * 64 + lm) * DI + lk;
        __builtin_amdgcn_s_setprio(1);
        #pragma unroll 4
        for (int kt = 0; kt < 8; ++kt) {
            const int ko = kt * 16;
            half8v a0  = *(const half8v*)(&sA[lm][ko + lk]);
            half8v a1  = *(const half8v*)(&sA[32 + lm][ko + lk]);
            half8v b0  = *(const half8v*)(w1p + ko);
            half8v b1f = *(const half8v*)(w1p + 32 * DI + ko);
            hacc[0][0] = __builtin_amdgcn_mfma_f32_32x32x16_f16(a0, b0,  hacc[0][0], 0, 0, 0);
            hacc[1][0] = __builtin_amdgcn_mfma_f32_32x32x16_f16(a1, b0,  hacc[1][0], 0, 0, 0);
            hacc[0][1] = __builtin_amdgcn_mfma_f32_32x32x16_f16(a0, b1f, hacc[0][1], 0, 0, 0);
            hacc[1][1] = __builtin_amdgcn_mfma_f32_32x32x16_f16(a1, b1f, hacc[1][1], 0, 0, 0);
        }
        __builtin_amdgcn_s_setprio(0);
    }

    // ---- epilogue: + b1 + P1[i] + P1[j], tanh, write sH ----
    {
        const float bias0 = b1[w * 64 + lm];
        const float bias1 = b1[w * 64 + 32 + lm];
        const float* p1c0 = P1 + (w * 64 + lm);        // + node*DH
        const float* p1c1 = P1 + (w * 64 + 32 + lm);
        #pragma unroll
        for (int mt = 0; mt < 2; ++mt) {
            #pragma unroll
            for (int r = 0; r < 16; ++r) {
                const int rl = mt * 32 + (r & 3) + 8 * (r >> 2) + rowq;
                const int2 ij = sIdx[rl];
                const size_t oi = (size_t)ij.x * DH;
                const size_t oj = (size_t)ij.y * DH;
                const float v0 = hacc[mt][0][r] + bias0 + p1c0[oi] + p1c0[oj];
                const float v1 = hacc[mt][1][r] + bias1 + p1c1[oi] + p1c1[oj];
                sH[rl][w * 64 + lm]      = (_Float16)fast_tanh(v0);
                sH[rl][w * 64 + 32 + lm] = (_Float16)fast_tanh(v1);
            }
        }
    }
    __syncthreads();

    // ---- GEMM2: out[64 x 128], wave w owns cols [w*32, w*32+32) ----
    floatx16 oacc[2] = {};
    {
        const _Float16* w2p = W2T + (size_t)(w * 32 + lm) * DH + lk;
        __builtin_amdgcn_s_setprio(1);
        #pragma unroll 4
        for (int kt = 0; kt < 16; ++kt) {
            const int ko = kt * 16;
            half8v a0 = *(const half8v*)(&sH[lm][ko + lk]);
            half8v a1 = *(const half8v*)(&sH[32 + lm][ko + lk]);
            half8v bb = *(const half8v*)(w2p + ko);
            oacc[0] = __builtin_amdgcn_mfma_f32_32x32x16_f16(a0, bb, oacc[0], 0, 0, 0);
            oacc[1] = __builtin_amdgcn_mfma_f32_32x32x16_f16(a1, bb, oacc[1], 0, 0, 0);
        }
        __builtin_amdgcn_s_setprio(0);
    }

    // ---- store: + b2, NT (write-once stream) ----
    {
        const int col = w * 32 + lm;
        const float bias = b2[col];
        #pragma unroll
        for (int mt = 0; mt < 2; ++mt) {
            #pragma unroll
            for (int r = 0; r < 16; ++r) {
                const int row = e0 + mt * 32 + (r & 3) + 8 * (r >> 2) + rowq;
                __builtin_nontemporal_store(oacc[mt][r] + bias,
                                            out + (size_t)row * DO + col);
            }
        }
    }
}

extern "C" void kernel_launch(void* const* d_in, const int* in_sizes, int n_in,
                              void* d_out, int out_size, void* d_ws, size_t ws_size,
                              hipStream_t stream) {
    const int*   idx_i = (const int*)d_in[0];
    const int*   idx_j = (const int*)d_in[1];
    const float* prop  = (const float*)d_in[2];
    const float* basis = (const float*)d_in[3];
    const float* W1    = (const float*)d_in[4];
    const float* b1    = (const float*)d_in[5];
    const float* W2    = (const float*)d_in[6];
    const float* b2    = (const float*)d_in[7];
    float* out = (float*)d_out;

    _Float16* W1T = (_Float16*)d_ws;                       // 64 KB
    _Float16* W2T = W1T + (size_t)DI * DH;                 // 64 KB
    float*    P1  = (float*)((char*)d_ws + 128 * 1024);    // 10.24 MB

    wconvert<<<64, 256, 0, stream>>>(W1, W2, W1T, W2T);
    p1comp<<<(N_NODES + TM - 1) / TM, 256, 0, stream>>>(prop, W1T, P1);
    pilayer_main<<<NBLK, 256, 0, stream>>>(idx_i, idx_j, basis, P1,
                                           W1T, b1, W2T, b2, out);
}